// Round 1
// baseline (222.081 us; speedup 1.0000x reference)
//
#include <hip/hip_runtime.h>
#include <hip/hip_bf16.h>

#define N_NODES 100000
#define N_EDGES 1000000
#define EMB 64
#define HID 64
#define VOCAB 128
#define N_GRAPHS 2048

#define CBUCKET 256                                    // nodes per bucket
#define NBK ((N_NODES + CBUCKET - 1) / CBUCKET)        // 391
#define CAP 4096                                       // slots per bucket (E[cnt]=2560, 30 sigma)
#define CHUNK 4096
#define SCAT_BLOCKS ((N_EDGES + CHUNK - 1) / CHUNK)    // 245
#define GB ((N_NODES + 255) / 256)                     // 391 gstart blocks

#define BCASTF(v, l) __int_as_float(__builtin_amdgcn_readlane(__float_as_int(v), (l)))

typedef __attribute__((ext_vector_type(8))) short short8;
typedef __attribute__((ext_vector_type(4))) float f32x4;
typedef __attribute__((ext_vector_type(2))) float f32x2;
typedef __attribute__((ext_vector_type(2))) unsigned int uint2v;

__device__ __forceinline__ float bf2f(unsigned short u) {
    return __uint_as_float((unsigned)u << 16);
}
__device__ __forceinline__ unsigned short f2bf(float f) {
    return __bfloat16_as_ushort(__float2bfloat16(f));
}

// float butterfly add via ds_swizzle (imm pattern, no VALU addr math)
#define SWZF(x, patt) __int_as_float(__builtin_amdgcn_ds_swizzle(__float_as_int(x), (patt)))

// ---- merged scatter + setup: blocks [0,245) scatter, [245,636) gstart,
//      [636,668) precompute. cursor/gsum pre-zeroed by one memset.
__global__ __launch_bounds__(256) void scatter_kernel(
    const int* __restrict__ src, const int* __restrict__ dst,
    const int* __restrict__ x,
    int* __restrict__ cursor, unsigned* __restrict__ edge8,
    const int* __restrict__ batch, int* __restrict__ gstart,
    const float* __restrict__ emb, const float* __restrict__ W1l,
    const float* __restrict__ W1r,
    const float* __restrict__ W2l, const float* __restrict__ W2r,
    float* __restrict__ embW1l, float* __restrict__ embW1r,
    unsigned short* __restrict__ w2frag, unsigned char* __restrict__ p8z)
{
    __shared__ unsigned earr[CHUNK];            // 16 KB packed payload
    __shared__ unsigned short karr[CHUNK];      // 8 KB bucket key (0..390)
    __shared__ int bcnt[NBK];
    __shared__ int bbase[NBK];
    int b = blockIdx.x;
    int t = threadIdx.x;

    if (b < SCAT_BLOCKS) {
        // ---- scatter: LDS-staged chunk, per-(block,bucket) run reservation
        // 32-bit payload: src(17) | x[src](7, bits 17..23) | local_dst(8, bits 24..31)
        for (int i = t; i < NBK; i += 256) bcnt[i] = 0;
        __syncthreads();
        int e0 = b * CHUNK;
        int n = min(e0 + CHUNK, N_EDGES) - e0;
        for (int i = t; i < n; i += 256) {
            int d = dst[e0 + i];
            int s = src[e0 + i];
            int xv = x[s];                      // random 4B read, 400KB L2-hot
            int k = d >> 8;
            earr[i] = (unsigned)s | ((unsigned)xv << 17) | ((unsigned)(d & 255) << 24);
            karr[i] = (unsigned short)k;
            atomicAdd(&bcnt[k], 1);
        }
        __syncthreads();
        for (int i = t; i < NBK; i += 256) {
            int c = bcnt[i];
            bbase[i] = i * CAP + (c ? atomicAdd(&cursor[i], c) : 0);
            bcnt[i] = 0;                        // reuse as local cursor
        }
        __syncthreads();
        for (int i = t; i < n; i += 256) {
            int k = karr[i];
            int off = atomicAdd(&bcnt[k], 1);
            edge8[bbase[k] + off] = earr[i];    // dense single-writer runs
        }
    } else if (b < SCAT_BLOCKS + GB) {
        // ---- graph boundaries (batch sorted)
        int i = (b - SCAT_BLOCKS) * 256 + t;
        if (i >= N_NODES) return;
        int bg = batch[i];
        int bp = (i == 0) ? -1 : batch[i - 1];
        for (int g = bp + 1; g <= bg; ++g) gstart[g] = i;
        if (i == N_NODES - 1)
            for (int g = bg + 1; g <= N_GRAPHS; ++g) gstart[g] = N_NODES;
    } else {
        // ---- precompute embW1l/embW1r + pack W2 B-fragments
        int vb = b - SCAT_BLOCKS - GB;
        // zero-row for sage2's branch-free gather (fp8 0x00 == +0.0)
        if (vb == 0 && t < 16)
            ((unsigned*)(p8z + (size_t)N_NODES * 64))[t] = 0u;
        int wave = t >> 6, lane = t & 63;
        int v = vb * 4 + wave;
        if (v < VOCAB) {
            float er = emb[v * 64 + lane];       // lane = d
            float al = 0.f, ar = 0.f;
#pragma unroll 8
            for (int d = 0; d < 64; ++d) {
                float e = BCASTF(er, d);
                al += e * W1l[d * 64 + lane];
                ar += e * W1r[d * 64 + lane];
            }
            embW1l[v * 64 + lane] = al;
            embW1r[v * 64 + lane] = ar;
        }
        // W2 B-fragment packing: g = tt*1024 + h*512 + l*8 + j
        int g = vb * 256 + t;
        int j = g & 7, l = (g >> 3) & 63, h = (g >> 9) & 1, tt = g >> 10;
        int k = h * 32 + ((l >> 4) * 8) + j;
        int n = tt * 16 + (l & 15);
        float w = (n < 64) ? W2l[k * 64 + n] : W2r[k * 64 + (n - 64)];
        w2frag[g] = f2bf(w);
    }
}

// ---- per-bucket CSR build (rowstart/deg/col), dense writes ------
// col entry = src (17b) | x[src] (7b) -> sage1 needs no x gather at all
__global__ __launch_bounds__(256) void csr_kernel(
    const unsigned* __restrict__ edge8, const int* __restrict__ cursor,
    int* __restrict__ row_start, int* __restrict__ deg, int* __restrict__ col)
{
    __shared__ int cnt[CBUCKET];
    __shared__ int scn[CBUCKET];
    int b = blockIdx.x;                   // NBK blocks
    int t = threadIdx.x;
    int lo = b * CAP, hi = lo + cursor[b];  // cursor holds final fill count
    cnt[t] = 0;
    __syncthreads();
    for (int i = lo + t; i < hi; i += 256)
        atomicAdd(&cnt[edge8[i] >> 24], 1);
    __syncthreads();
    int v = cnt[t];
    scn[t] = v;
    __syncthreads();
    for (int off = 1; off < 256; off <<= 1) {
        int tmp = (t >= off) ? scn[t - off] : 0;
        __syncthreads();
        scn[t] += tmp;
        __syncthreads();
    }
    int excl = scn[t] - v;
    int node = b * CBUCKET + t;
    if (node < N_NODES) { row_start[node] = lo + excl; deg[node] = v; }
    cnt[t] = excl;                        // reuse as cursor
    __syncthreads();
    for (int i = lo + t; i < hi; i += 256) {
        unsigned e = edge8[i];
        int slot = atomicAdd(&cnt[e >> 24], 1);
        col[lo + slot] = (int)(e & 0xFFFFFF);   // src | x<<17 (24 bits)
    }
}

// ---- fused layer 1 + MFMA transform:
//   phase A: h1 = relu(mean_j(embW1l[x_j]) + b1 + embW1r[x_i])  ((c,g) layout,
//            ds_read_b128: one wave-instr covers 4 rows, 8 rows in flight)
//   phase B: [p|q] = h1 @ [W2l|W2r] via mfma_16x16x32_bf16; msbuf aliases elds
#define S1_NPW 8
__global__ __launch_bounds__(256) void sage1_kernel(
    const int* __restrict__ x, const float* __restrict__ embW1l,
    const float* __restrict__ embW1r, const float* __restrict__ b1,
    const int* __restrict__ row_start, const int* __restrict__ deg,
    const int* __restrict__ col, const unsigned short* __restrict__ w2frag,
    unsigned char* __restrict__ p8, unsigned short* __restrict__ q16)
{
    __shared__ float elds[VOCAB * 64];      // 32 KB; phase B aliases as msbuf
    int t = threadIdx.x;
    for (int i = t * 4; i < VOCAB * 64; i += 1024)
        *(float4*)&elds[i] = *(const float4*)&embW1l[i];
    __syncthreads();

    int wave = t >> 6, lane = t & 63;
    int block_base = blockIdx.x * (4 * S1_NPW);         // 3125*32 = 100000 exact
    int base_node = block_base + wave * S1_NPW;
    int c = lane & 15;          // feature quad: features 4c..4c+3
    int g = lane >> 4;          // row group 0..3
    float4 bias4 = ((const float4*)b1)[c];

    int rs[S1_NPW], dgs[S1_NPW], cidx[S1_NPW], xn[S1_NPW];
    float4 self4[S1_NPW];
#pragma unroll
    for (int n = 0; n < S1_NPW; ++n) {
        rs[n] = row_start[base_node + n];
        dgs[n] = deg[base_node + n];
        xn[n] = x[base_node + n];
    }
#pragma unroll
    for (int n = 0; n < S1_NPW; ++n) {
        cidx[n] = (lane < dgs[n]) ? col[rs[n] + lane] : 0;
        self4[n] = ((const float4*)(embW1r + xn[n] * 64))[c];
    }

    unsigned short* msbuf = (unsigned short*)elds;      // [32][72], aliases elds
    ushort4 h1row[S1_NPW];                              // lane's 4 features per node

    for (int n = 0; n < S1_NPW; ++n) {
        int dg = dgs[n];
        int dgc = (dg < 64) ? dg : 64;

        // 2 x ds_read_b128 per iter; each covers 4 rows across the groups
        float4 a0 = {0.f,0.f,0.f,0.f}, a1 = {0.f,0.f,0.f,0.f};
        for (int j = 0; j < dgc; j += 8) {
            int jj0 = j + g, jj1 = j + 4 + g;           // < 64 always
            int x0 = __shfl(cidx[n], jj0, 64) >> 17;
            int x1 = __shfl(cidx[n], jj1, 64) >> 17;
            float4 v0 = *(const float4*)&elds[x0 * 64 + c * 4];
            float4 v1 = *(const float4*)&elds[x1 * 64 + c * 4];
            if (jj0 < dgc) { a0.x += v0.x; a0.y += v0.y; a0.z += v0.z; a0.w += v0.w; }
            if (jj1 < dgc) { a1.x += v1.x; a1.y += v1.y; a1.z += v1.z; a1.w += v1.w; }
        }
        for (int k = 64; k < dg; ++k) {                 // deg>64 tail (rare)
            int cc = col[rs[n] + k] >> 17;
            float4 v = *(const float4*)&elds[cc * 64 + c * 4];
            if (g == 0) { a0.x += v.x; a0.y += v.y; a0.z += v.z; a0.w += v.w; }
        }
        float sx = a0.x + a1.x, sy = a0.y + a1.y, sz = a0.z + a1.z, sw = a0.w + a1.w;
        sx += __shfl_xor(sx, 16, 64); sx += __shfl_xor(sx, 32, 64);
        sy += __shfl_xor(sy, 16, 64); sy += __shfl_xor(sy, 32, 64);
        sz += __shfl_xor(sz, 16, 64); sz += __shfl_xor(sz, 32, 64);
        sw += __shfl_xor(sw, 16, 64); sw += __shfl_xor(sw, 32, 64);

        float inv = 1.0f / fmaxf((float)dg, 1.0f);
        h1row[n].x = f2bf(fmaxf(sx * inv + bias4.x + self4[n].x, 0.f));
        h1row[n].y = f2bf(fmaxf(sy * inv + bias4.y + self4[n].y, 0.f));
        h1row[n].z = f2bf(fmaxf(sz * inv + bias4.z + self4[n].z, 0.f));
        h1row[n].w = f2bf(fmaxf(sw * inv + bias4.w + self4[n].w, 0.f));
    }
    __syncthreads();                        // all elds reads complete

    // stage h1 rows into msbuf (stride 72 -> 16B-aligned rows); g==0 writes
    if (g == 0) {
#pragma unroll
        for (int n = 0; n < S1_NPW; ++n)
            *(ushort4*)&msbuf[(wave * S1_NPW + n) * 72 + c * 4] = h1row[n];
    }
    __syncthreads();

    // phase B: wave -> node-group (wave>>1), output tiles (wave&1)*4..+3
    int grp = wave >> 1, tbase = (wave & 1) * 4;
    int m = lane & 15, quad = lane >> 4;
    int base16g = block_base + grp * 16;
    const unsigned short* arow = &msbuf[(grp * 16 + m) * 72 + quad * 8];
    short8 a0 = *(const short8*)(arow);                 // k = quad*8 .. +7
    short8 a1 = *(const short8*)(arow + 32);            // k = 32+quad*8 .. +7

#pragma unroll
    for (int tt = tbase; tt < tbase + 4; ++tt) {
        short8 b0 = *(const short8*)(w2frag + tt * 1024 + lane * 8);
        short8 b1v = *(const short8*)(w2frag + tt * 1024 + 512 + lane * 8);
        f32x4 acc = {0.f, 0.f, 0.f, 0.f};
        acc = __builtin_amdgcn_mfma_f32_16x16x32_bf16(a0, b0, acc, 0, 0, 0);
        acc = __builtin_amdgcn_mfma_f32_16x16x32_bf16(a1, b1v, acc, 0, 0, 0);
        int o = tt * 16 + m;
        if (o < 64) {
            int pk01 = __builtin_amdgcn_cvt_pk_fp8_f32(acc[0], acc[1], 0, false);
            int pk23 = __builtin_amdgcn_cvt_pk_fp8_f32(acc[2], acc[3], 0, false);
            p8[(base16g + quad * 4 + 0) * 64 + o] = (unsigned char)(pk01 & 0xff);
            p8[(base16g + quad * 4 + 1) * 64 + o] = (unsigned char)((pk01 >> 8) & 0xff);
            p8[(base16g + quad * 4 + 2) * 64 + o] = (unsigned char)(pk23 & 0xff);
            p8[(base16g + quad * 4 + 3) * 64 + o] = (unsigned char)((pk23 >> 8) & 0xff);
        } else {
            int oc = o & 63;
#pragma unroll
            for (int i = 0; i < 4; ++i)
                q16[(base16g + quad * 4 + i) * 64 + oc] = f2bf(acc[i]);
        }
    }
}

// ---- sage2, group-per-node layout:
//   lane = g8*8 + c8: group g8 owns node (wave*8+g8); lane owns features 8c8..8c8+7.
//   16-row gather window: 16 independent 8B/lane loads in flight (vs 2 before),
//   rows >= deg read a zeroed row (fp8 0x00 = +0.0) -> branch-free accumulate.
//   No cross-group feature reduce; epilogue computed once per node (8 lanes).
//   h2 = relu(mean_j p_j + b2 + q_i); gsum[batch] += h2 @ Wout
__global__ __launch_bounds__(256, 6) void sage2_kernel(
    const unsigned char* __restrict__ p, const unsigned short* __restrict__ q,
    const int* __restrict__ row_start, const int* __restrict__ deg,
    const int* __restrict__ col, const float* __restrict__ b2,
    const float* __restrict__ Wout, const int* __restrict__ batch,
    float* __restrict__ gsum)
{
    int t = threadIdx.x;
    int wave = t >> 6, lane = t & 63;
    int c8 = lane & 7;                      // feature octet: features 8c8..8c8+7
    int node = (blockIdx.x * 4 + wave) * 8 + (lane >> 3);   // 3125*32 = 100000 exact

    int rs = row_start[node];
    int dg = deg[node];
    int grp = batch[node];

    float4 accA = {0.f,0.f,0.f,0.f}, accB = {0.f,0.f,0.f,0.f};
    int r0 = 0;
    while (true) {
        // per-16-row window: lane c8 of each group holds col entries r0+c8, r0+c8+8
        int cid0 = (r0 + c8     < dg) ? (col[rs + r0 + c8    ] & 0x1FFFF) : N_NODES;
        int cid1 = (r0 + c8 + 8 < dg) ? (col[rs + r0 + c8 + 8] & 0x1FFFF) : N_NODES;

        uint2v v[16];
        // ds_swizzle broadcast within 8-lane group: src = (l & 0x18) | r (imm pattern)
#define GATHER(r, cidv, slot) { \
        int i_ = __builtin_amdgcn_ds_swizzle((cidv), (((r) << 5) | 0x18)); \
        v[slot] = *(const uint2v*)(p + ((size_t)i_ << 6) + (c8 << 3)); }
        GATHER(0, cid0, 0)  GATHER(1, cid0, 1)  GATHER(2, cid0, 2)  GATHER(3, cid0, 3)
        GATHER(4, cid0, 4)  GATHER(5, cid0, 5)  GATHER(6, cid0, 6)  GATHER(7, cid0, 7)
        GATHER(0, cid1, 8)  GATHER(1, cid1, 9)  GATHER(2, cid1, 10) GATHER(3, cid1, 11)
        GATHER(4, cid1, 12) GATHER(5, cid1, 13) GATHER(6, cid1, 14) GATHER(7, cid1, 15)
#undef GATHER

#pragma unroll
        for (int r = 0; r < 16; ++r) {
            f32x2 f01 = __builtin_amdgcn_cvt_pk_f32_fp8((int)v[r].x, false);
            f32x2 f23 = __builtin_amdgcn_cvt_pk_f32_fp8((int)v[r].x, true);
            f32x2 f45 = __builtin_amdgcn_cvt_pk_f32_fp8((int)v[r].y, false);
            f32x2 f67 = __builtin_amdgcn_cvt_pk_f32_fp8((int)v[r].y, true);
            accA.x += f01.x; accA.y += f01.y; accA.z += f23.x; accA.w += f23.y;
            accB.x += f45.x; accB.y += f45.y; accB.z += f67.x; accB.w += f67.y;
        }
        r0 += 16;
        if (r0 >= dg) break;                // group-uniform exit
    }

    // ---- epilogue: one pass per node, 8 lanes x 8 features ----
    float inv = 1.0f / fmaxf((float)dg, 1.0f);
    const float4* b2p = (const float4*)b2 + (c8 << 1);
    float4 b2a = b2p[0], b2b = b2p[1];
    short8 qv = *(const short8*)(q + ((size_t)node << 6) + (c8 << 3));
    float h0 = fmaxf(accA.x * inv + b2a.x + bf2f((unsigned short)qv[0]), 0.f);
    float h1 = fmaxf(accA.y * inv + b2a.y + bf2f((unsigned short)qv[1]), 0.f);
    float h2 = fmaxf(accA.z * inv + b2a.z + bf2f((unsigned short)qv[2]), 0.f);
    float h3 = fmaxf(accA.w * inv + b2a.w + bf2f((unsigned short)qv[3]), 0.f);
    float h4 = fmaxf(accB.x * inv + b2b.x + bf2f((unsigned short)qv[4]), 0.f);
    float h5 = fmaxf(accB.y * inv + b2b.y + bf2f((unsigned short)qv[5]), 0.f);
    float h6 = fmaxf(accB.z * inv + b2b.z + bf2f((unsigned short)qv[6]), 0.f);
    float h7 = fmaxf(accB.w * inv + b2b.w + bf2f((unsigned short)qv[7]), 0.f);

    const float4* wv = (const float4*)Wout + (c8 << 2);   // rows 8c8..8c8+7 of [64][2]
    float4 wa = wv[0], wb = wv[1], wc = wv[2], wd = wv[3];
    float s0 = h0*wa.x + h1*wa.z + h2*wb.x + h3*wb.z + h4*wc.x + h5*wc.z + h6*wd.x + h7*wd.z;
    float s1 = h0*wa.y + h1*wa.w + h2*wb.y + h3*wb.w + h4*wc.y + h5*wc.w + h6*wd.y + h7*wd.w;

    // butterfly within the 8-lane group (imm ds_swizzle xor 4,2,1)
    s0 += SWZF(s0, 0x101F); s1 += SWZF(s1, 0x101F);
    s0 += SWZF(s0, 0x081F); s1 += SWZF(s1, 0x081F);
    s0 += SWZF(s0, 0x041F); s1 += SWZF(s1, 0x041F);
    if (c8 == 0) {
        atomicAdd(&gsum[(grp << 1) + 0], s0);
        atomicAdd(&gsum[(grp << 1) + 1], s1);
    }
}

// ---------------- finalize: out = gsum/cnt + bout ----------------
__global__ __launch_bounds__(256) void finalize_kernel(
    const float* __restrict__ gsum, const int* __restrict__ gstart,
    const float* __restrict__ bout, float* __restrict__ out)
{
    int g = blockIdx.x * 256 + threadIdx.x;
    if (g >= N_GRAPHS) return;
    int cnt = gstart[g + 1] - gstart[g];
    float inv = 1.0f / fmaxf((float)cnt, 1.0f);
    out[g * 2 + 0] = gsum[g * 2 + 0] * inv + bout[0];
    out[g * 2 + 1] = gsum[g * 2 + 1] * inv + bout[1];
}

extern "C" void kernel_launch(void* const* d_in, const int* in_sizes, int n_in,
                              void* d_out, int out_size, void* d_ws, size_t ws_size,
                              hipStream_t stream) {
    const int*   x    = (const int*)  d_in[0];
    const int*   ei   = (const int*)  d_in[1];
    const int*   batch= (const int*)  d_in[2];
    const float* emb  = (const float*)d_in[3];
    const float* W1l  = (const float*)d_in[4];
    const float* b1   = (const float*)d_in[5];
    const float* W1r  = (const float*)d_in[6];
    const float* W2l  = (const float*)d_in[7];
    const float* b2   = (const float*)d_in[8];
    const float* W2r  = (const float*)d_in[9];
    const float* Wout = (const float*)d_in[10];
    const float* bout = (const float*)d_in[11];
    float* out = (float*)d_out;

    const int* src = ei;
    const int* dst = ei + N_EDGES;

    char* ws = (char*)d_ws;
    size_t off = 0;
    unsigned char*  p8     = (unsigned char*) (ws + off); off += (size_t)N_NODES * 64 + 64; // +64B zero row
    unsigned short* q16    = (unsigned short*)(ws + off); off += (size_t)N_NODES * 64 * 2;  // 12.8 MB
    unsigned short* w2frag = (unsigned short*)(ws + off); off += (size_t)8192 * 2;
    float*    embW1l = (float*)   (ws + off); off += (size_t)VOCAB * 64 * 4;
    float*    embW1r = (float*)   (ws + off); off += (size_t)VOCAB * 64 * 4;
    int*      rowst  = (int*)     (ws + off); off += (size_t)N_NODES * 4;
    int*      deg    = (int*)     (ws + off); off += (size_t)N_NODES * 4;
    int*      col    = (int*)     (ws + off); off += (size_t)(NBK * CAP + 256) * 4;   // 6.4 MB
    unsigned* edge8  = (unsigned*)(ws + off); off += (size_t)NBK * CAP * 4;           // 6.4 MB
    int*      gstart = (int*)     (ws + off); off += (size_t)(N_GRAPHS + 1) * 4;
    // contiguous zero region: cursor | gsum (one memset)
    int*      cursor = (int*)     (ws + off); off += (size_t)NBK * 4;
    float*    gsum   = (float*)   (ws + off); off += (size_t)N_GRAPHS * 2 * 4;

    hipMemsetAsync(cursor, 0, (size_t)NBK * 4 + (size_t)N_GRAPHS * 2 * 4, stream);

    scatter_kernel<<<SCAT_BLOCKS + GB + 32, 256, 0, stream>>>(
        src, dst, x, cursor, edge8,
        batch, gstart, emb, W1l, W1r, W2l, W2r, embW1l, embW1r, w2frag, p8);
    csr_kernel<<<NBK, 256, 0, stream>>>(edge8, cursor, rowst, deg, col);
    sage1_kernel<<<N_NODES / (4 * S1_NPW), 256, 0, stream>>>(
        x, embW1l, embW1r, b1, rowst, deg, col, w2frag, p8, q16);
    sage2_kernel<<<N_NODES / 32, 256, 0, stream>>>(
        p8, q16, rowst, deg, col, b2, Wout, batch, gsum);
    finalize_kernel<<<(N_GRAPHS + 255) / 256, 256, 0, stream>>>(gsum, gstart, bout, out);
}

// Round 2
// 209.241 us; speedup vs baseline: 1.0614x; 1.0614x over previous
//
#include <hip/hip_runtime.h>
#include <hip/hip_bf16.h>

#define N_NODES 100000
#define N_EDGES 1000000
#define EMB 64
#define HID 64
#define VOCAB 128
#define N_GRAPHS 2048

#define CBUCKET 256                                    // nodes per bucket
#define NBK ((N_NODES + CBUCKET - 1) / CBUCKET)        // 391
#define CAP 4096                                       // slots per bucket (E[cnt]=2560, 30 sigma)
#define CHUNK 4096
#define SCAT_BLOCKS ((N_EDGES + CHUNK - 1) / CHUNK)    // 245
#define GB ((N_NODES + 255) / 256)                     // 391 gstart blocks

#define BCASTF(v, l) __int_as_float(__builtin_amdgcn_readlane(__float_as_int(v), (l)))

typedef __attribute__((ext_vector_type(8))) short short8;
typedef __attribute__((ext_vector_type(4))) float f32x4;
typedef __attribute__((ext_vector_type(2))) float f32x2;

__device__ __forceinline__ float bf2f(unsigned short u) {
    return __uint_as_float((unsigned)u << 16);
}
__device__ __forceinline__ unsigned short f2bf(float f) {
    return __bfloat16_as_ushort(__float2bfloat16(f));
}

// ---- merged scatter + setup: blocks [0,245) scatter, [245,636) gstart,
//      [636,668) precompute. cursor/gsum pre-zeroed by one memset.
__global__ __launch_bounds__(256) void scatter_kernel(
    const int* __restrict__ src, const int* __restrict__ dst,
    const int* __restrict__ x,
    int* __restrict__ cursor, unsigned* __restrict__ edge8,
    const int* __restrict__ batch, int* __restrict__ gstart,
    const float* __restrict__ emb, const float* __restrict__ W1l,
    const float* __restrict__ W1r,
    const float* __restrict__ W2l, const float* __restrict__ W2r,
    float* __restrict__ embW1l, float* __restrict__ embW1r,
    unsigned short* __restrict__ w2frag, unsigned char* __restrict__ p8z)
{
    __shared__ unsigned earr[CHUNK];            // 16 KB packed payload
    __shared__ unsigned short karr[CHUNK];      // 8 KB bucket key (0..390)
    __shared__ int bcnt[NBK];
    __shared__ int bbase[NBK];
    int b = blockIdx.x;
    int t = threadIdx.x;

    if (b < SCAT_BLOCKS) {
        // ---- scatter: LDS-staged chunk, per-(block,bucket) run reservation
        // 32-bit payload: src(17) | x[src](7, bits 17..23) | local_dst(8, bits 24..31)
        for (int i = t; i < NBK; i += 256) bcnt[i] = 0;
        __syncthreads();
        int e0 = b * CHUNK;
        int n = min(e0 + CHUNK, N_EDGES) - e0;
        for (int i = t; i < n; i += 256) {
            int d = dst[e0 + i];
            int s = src[e0 + i];
            int xv = x[s];                      // random 4B read, 400KB L2-hot
            int k = d >> 8;
            earr[i] = (unsigned)s | ((unsigned)xv << 17) | ((unsigned)(d & 255) << 24);
            karr[i] = (unsigned short)k;
            atomicAdd(&bcnt[k], 1);
        }
        __syncthreads();
        for (int i = t; i < NBK; i += 256) {
            int c = bcnt[i];
            bbase[i] = i * CAP + (c ? atomicAdd(&cursor[i], c) : 0);
            bcnt[i] = 0;                        // reuse as local cursor
        }
        __syncthreads();
        for (int i = t; i < n; i += 256) {
            int k = karr[i];
            int off = atomicAdd(&bcnt[k], 1);
            edge8[bbase[k] + off] = earr[i];    // dense single-writer runs
        }
    } else if (b < SCAT_BLOCKS + GB) {
        // ---- graph boundaries (batch sorted)
        int i = (b - SCAT_BLOCKS) * 256 + t;
        if (i >= N_NODES) return;
        int bg = batch[i];
        int bp = (i == 0) ? -1 : batch[i - 1];
        for (int g = bp + 1; g <= bg; ++g) gstart[g] = i;
        if (i == N_NODES - 1)
            for (int g = bg + 1; g <= N_GRAPHS; ++g) gstart[g] = N_NODES;
    } else {
        // ---- precompute embW1l/embW1r + pack W2 B-fragments
        int vb = b - SCAT_BLOCKS - GB;
        // zero-row for sage2's branch-free gather (fp8 0x00 == +0.0)
        if (vb == 0 && t < 16)
            ((unsigned*)(p8z + (size_t)N_NODES * 64))[t] = 0u;
        int wave = t >> 6, lane = t & 63;
        int v = vb * 4 + wave;
        if (v < VOCAB) {
            float er = emb[v * 64 + lane];       // lane = d
            float al = 0.f, ar = 0.f;
#pragma unroll 8
            for (int d = 0; d < 64; ++d) {
                float e = BCASTF(er, d);
                al += e * W1l[d * 64 + lane];
                ar += e * W1r[d * 64 + lane];
            }
            embW1l[v * 64 + lane] = al;
            embW1r[v * 64 + lane] = ar;
        }
        // W2 B-fragment packing: g = tt*1024 + h*512 + l*8 + j
        int g = vb * 256 + t;
        int j = g & 7, l = (g >> 3) & 63, h = (g >> 9) & 1, tt = g >> 10;
        int k = h * 32 + ((l >> 4) * 8) + j;
        int n = tt * 16 + (l & 15);
        float w = (n < 64) ? W2l[k * 64 + n] : W2r[k * 64 + (n - 64)];
        w2frag[g] = f2bf(w);
    }
}

// ---- per-bucket CSR build (rowstart/deg/col), dense writes ------
// col entry = src (17b) | x[src] (7b) -> sage1 needs no x gather at all
__global__ __launch_bounds__(256) void csr_kernel(
    const unsigned* __restrict__ edge8, const int* __restrict__ cursor,
    int* __restrict__ row_start, int* __restrict__ deg, int* __restrict__ col)
{
    __shared__ int cnt[CBUCKET];
    __shared__ int scn[CBUCKET];
    int b = blockIdx.x;                   // NBK blocks
    int t = threadIdx.x;
    int lo = b * CAP, hi = lo + cursor[b];  // cursor holds final fill count
    cnt[t] = 0;
    __syncthreads();
    for (int i = lo + t; i < hi; i += 256)
        atomicAdd(&cnt[edge8[i] >> 24], 1);
    __syncthreads();
    int v = cnt[t];
    scn[t] = v;
    __syncthreads();
    for (int off = 1; off < 256; off <<= 1) {
        int tmp = (t >= off) ? scn[t - off] : 0;
        __syncthreads();
        scn[t] += tmp;
        __syncthreads();
    }
    int excl = scn[t] - v;
    int node = b * CBUCKET + t;
    if (node < N_NODES) { row_start[node] = lo + excl; deg[node] = v; }
    cnt[t] = excl;                        // reuse as cursor
    __syncthreads();
    for (int i = lo + t; i < hi; i += 256) {
        unsigned e = edge8[i];
        int slot = atomicAdd(&cnt[e >> 24], 1);
        col[lo + slot] = (int)(e & 0xFFFFFF);   // src | x<<17 (24 bits)
    }
}

// ---- fused layer 1 + MFMA transform:
//   phase A: h1 = relu(mean_j(embW1l[x_j]) + b1 + embW1r[x_i])  ((c,g) layout,
//            ds_read_b128: one wave-instr covers 4 rows, 8 rows in flight)
//   phase B: [p|q] = h1 @ [W2l|W2r] via mfma_16x16x32_bf16; msbuf aliases elds
#define S1_NPW 8
__global__ __launch_bounds__(256) void sage1_kernel(
    const int* __restrict__ x, const float* __restrict__ embW1l,
    const float* __restrict__ embW1r, const float* __restrict__ b1,
    const int* __restrict__ row_start, const int* __restrict__ deg,
    const int* __restrict__ col, const unsigned short* __restrict__ w2frag,
    unsigned char* __restrict__ p8, unsigned short* __restrict__ q16)
{
    __shared__ float elds[VOCAB * 64];      // 32 KB; phase B aliases as msbuf
    int t = threadIdx.x;
    for (int i = t * 4; i < VOCAB * 64; i += 1024)
        *(float4*)&elds[i] = *(const float4*)&embW1l[i];
    __syncthreads();

    int wave = t >> 6, lane = t & 63;
    int block_base = blockIdx.x * (4 * S1_NPW);         // 3125*32 = 100000 exact
    int base_node = block_base + wave * S1_NPW;
    int c = lane & 15;          // feature quad: features 4c..4c+3
    int g = lane >> 4;          // row group 0..3
    float4 bias4 = ((const float4*)b1)[c];

    int rs[S1_NPW], dgs[S1_NPW], cidx[S1_NPW], xn[S1_NPW];
    float4 self4[S1_NPW];
#pragma unroll
    for (int n = 0; n < S1_NPW; ++n) {
        rs[n] = row_start[base_node + n];
        dgs[n] = deg[base_node + n];
        xn[n] = x[base_node + n];
    }
#pragma unroll
    for (int n = 0; n < S1_NPW; ++n) {
        cidx[n] = (lane < dgs[n]) ? col[rs[n] + lane] : 0;
        self4[n] = ((const float4*)(embW1r + xn[n] * 64))[c];
    }

    unsigned short* msbuf = (unsigned short*)elds;      // [32][72], aliases elds
    ushort4 h1row[S1_NPW];                              // lane's 4 features per node

    for (int n = 0; n < S1_NPW; ++n) {
        int dg = dgs[n];
        int dgc = (dg < 64) ? dg : 64;

        // 2 x ds_read_b128 per iter; each covers 4 rows across the groups
        float4 a0 = {0.f,0.f,0.f,0.f}, a1 = {0.f,0.f,0.f,0.f};
        for (int j = 0; j < dgc; j += 8) {
            int jj0 = j + g, jj1 = j + 4 + g;           // < 64 always
            int x0 = __shfl(cidx[n], jj0, 64) >> 17;
            int x1 = __shfl(cidx[n], jj1, 64) >> 17;
            float4 v0 = *(const float4*)&elds[x0 * 64 + c * 4];
            float4 v1 = *(const float4*)&elds[x1 * 64 + c * 4];
            if (jj0 < dgc) { a0.x += v0.x; a0.y += v0.y; a0.z += v0.z; a0.w += v0.w; }
            if (jj1 < dgc) { a1.x += v1.x; a1.y += v1.y; a1.z += v1.z; a1.w += v1.w; }
        }
        for (int k = 64; k < dg; ++k) {                 // deg>64 tail (rare)
            int cc = col[rs[n] + k] >> 17;
            float4 v = *(const float4*)&elds[cc * 64 + c * 4];
            if (g == 0) { a0.x += v.x; a0.y += v.y; a0.z += v.z; a0.w += v.w; }
        }
        float sx = a0.x + a1.x, sy = a0.y + a1.y, sz = a0.z + a1.z, sw = a0.w + a1.w;
        sx += __shfl_xor(sx, 16, 64); sx += __shfl_xor(sx, 32, 64);
        sy += __shfl_xor(sy, 16, 64); sy += __shfl_xor(sy, 32, 64);
        sz += __shfl_xor(sz, 16, 64); sz += __shfl_xor(sz, 32, 64);
        sw += __shfl_xor(sw, 16, 64); sw += __shfl_xor(sw, 32, 64);

        float inv = 1.0f / fmaxf((float)dg, 1.0f);
        h1row[n].x = f2bf(fmaxf(sx * inv + bias4.x + self4[n].x, 0.f));
        h1row[n].y = f2bf(fmaxf(sy * inv + bias4.y + self4[n].y, 0.f));
        h1row[n].z = f2bf(fmaxf(sz * inv + bias4.z + self4[n].z, 0.f));
        h1row[n].w = f2bf(fmaxf(sw * inv + bias4.w + self4[n].w, 0.f));
    }
    __syncthreads();                        // all elds reads complete

    // stage h1 rows into msbuf (stride 72 -> 16B-aligned rows); g==0 writes
    if (g == 0) {
#pragma unroll
        for (int n = 0; n < S1_NPW; ++n)
            *(ushort4*)&msbuf[(wave * S1_NPW + n) * 72 + c * 4] = h1row[n];
    }
    __syncthreads();

    // phase B: wave -> node-group (wave>>1), output tiles (wave&1)*4..+3
    int grp = wave >> 1, tbase = (wave & 1) * 4;
    int m = lane & 15, quad = lane >> 4;
    int base16g = block_base + grp * 16;
    const unsigned short* arow = &msbuf[(grp * 16 + m) * 72 + quad * 8];
    short8 a0 = *(const short8*)(arow);                 // k = quad*8 .. +7
    short8 a1 = *(const short8*)(arow + 32);            // k = 32+quad*8 .. +7

#pragma unroll
    for (int tt = tbase; tt < tbase + 4; ++tt) {
        short8 b0 = *(const short8*)(w2frag + tt * 1024 + lane * 8);
        short8 b1v = *(const short8*)(w2frag + tt * 1024 + 512 + lane * 8);
        f32x4 acc = {0.f, 0.f, 0.f, 0.f};
        acc = __builtin_amdgcn_mfma_f32_16x16x32_bf16(a0, b0, acc, 0, 0, 0);
        acc = __builtin_amdgcn_mfma_f32_16x16x32_bf16(a1, b1v, acc, 0, 0, 0);
        int o = tt * 16 + m;
        if (o < 64) {
            int pk01 = __builtin_amdgcn_cvt_pk_fp8_f32(acc[0], acc[1], 0, false);
            int pk23 = __builtin_amdgcn_cvt_pk_fp8_f32(acc[2], acc[3], 0, false);
            p8[(base16g + quad * 4 + 0) * 64 + o] = (unsigned char)(pk01 & 0xff);
            p8[(base16g + quad * 4 + 1) * 64 + o] = (unsigned char)((pk01 >> 8) & 0xff);
            p8[(base16g + quad * 4 + 2) * 64 + o] = (unsigned char)(pk23 & 0xff);
            p8[(base16g + quad * 4 + 3) * 64 + o] = (unsigned char)((pk23 >> 8) & 0xff);
        } else {
            int oc = o & 63;
#pragma unroll
            for (int i = 0; i < 4; ++i)
                q16[(base16g + quad * 4 + i) * 64 + oc] = f2bf(acc[i]);
        }
    }
}

// ---- sage2: round-0 proven layout (16 lanes/row, shfl addr broadcast),
//   widened to NODE PAIRS with a fixed 16-row window:
//   8 independent 4B gathers in flight per vmcnt wait (was 2), ~5 serial
//   waits/wave (was ~16). cidx pre-masked to the zero row -> unconditional
//   adds (fp8 0x00 = +0.0). Tails: deg in (16,64] 8-row windows; deg>64 scalar.
//   h2 = relu(mean_j p_j + b2 + q_i); gsum[batch] += h2 @ Wout
#define S2_NPW 8
#define ZROW N_NODES
__global__ __launch_bounds__(256, 6) void sage2_kernel(
    const unsigned char* __restrict__ p, const unsigned short* __restrict__ q,
    const int* __restrict__ row_start, const int* __restrict__ deg,
    const int* __restrict__ col, const float* __restrict__ b2,
    const float* __restrict__ Wout, const int* __restrict__ batch,
    float* __restrict__ gsum)
{
    int t = threadIdx.x;
    int wave = t >> 6, lane = t & 63;
    int base_node = (blockIdx.x * 4 + wave) * S2_NPW;   // exact cover
    int c = lane & 15;          // feature quad: features 4c..4c+3
    int g = lane >> 4;          // row group 0..3

    float4 b2v = ((const float4*)b2)[c];
    float4 w01 = ((const float4*)Wout)[c * 2];
    float4 w23 = ((const float4*)Wout)[c * 2 + 1];

    // prefetch per-node metadata + neighbor index rows for all 8 nodes;
    // lanes >= deg hold the zero row -> shfl'd OOB rows load +0.0 rows
    int rs[S2_NPW], dgs[S2_NPW], cidx[S2_NPW];
#pragma unroll
    for (int n = 0; n < S2_NPW; ++n) {
        rs[n] = row_start[base_node + n];
        dgs[n] = deg[base_node + n];
    }
#pragma unroll
    for (int n = 0; n < S2_NPW; ++n)
        cidx[n] = (lane < dgs[n]) ? (col[rs[n] + lane] & 0x1FFFF) : ZROW;

#define ACC(a, v) { f32x2 f01_ = __builtin_amdgcn_cvt_pk_f32_fp8((int)(v), false); \
                    f32x2 f23_ = __builtin_amdgcn_cvt_pk_f32_fp8((int)(v), true);  \
                    (a).x += f01_.x; (a).y += f01_.y; (a).z += f23_.x; (a).w += f23_.y; }

#pragma unroll
    for (int n = 0; n < S2_NPW; n += 2) {
        int dgA = dgs[n], dgB = dgs[n + 1];

        // --- 16-row window for BOTH nodes: rows g, 4+g, 8+g, 12+g each ---
        int iA0 = __shfl(cidx[n], g, 64);
        int iA1 = __shfl(cidx[n], 4 + g, 64);
        int iA2 = __shfl(cidx[n], 8 + g, 64);
        int iA3 = __shfl(cidx[n], 12 + g, 64);
        int iB0 = __shfl(cidx[n + 1], g, 64);
        int iB1 = __shfl(cidx[n + 1], 4 + g, 64);
        int iB2 = __shfl(cidx[n + 1], 8 + g, 64);
        int iB3 = __shfl(cidx[n + 1], 12 + g, 64);

        unsigned vA0 = *(const unsigned*)(p + (size_t)iA0 * 64 + c * 4);
        unsigned vA1 = *(const unsigned*)(p + (size_t)iA1 * 64 + c * 4);
        unsigned vA2 = *(const unsigned*)(p + (size_t)iA2 * 64 + c * 4);
        unsigned vA3 = *(const unsigned*)(p + (size_t)iA3 * 64 + c * 4);
        unsigned vB0 = *(const unsigned*)(p + (size_t)iB0 * 64 + c * 4);
        unsigned vB1 = *(const unsigned*)(p + (size_t)iB1 * 64 + c * 4);
        unsigned vB2 = *(const unsigned*)(p + (size_t)iB2 * 64 + c * 4);
        unsigned vB3 = *(const unsigned*)(p + (size_t)iB3 * 64 + c * 4);

        float4 aA = {0.f,0.f,0.f,0.f}, aB = {0.f,0.f,0.f,0.f};
        ACC(aA, vA0) ACC(aA, vA1) ACC(aA, vA2) ACC(aA, vA3)
        ACC(aB, vB0) ACC(aB, vB1) ACC(aB, vB2) ACC(aB, vB3)

        // --- deg in (16,64] tail: 8-row windows, 2 loads each (rare) ---
        for (int j = 16; j < dgA; j += 8) {
            int i0 = __shfl(cidx[n], j + g, 64);        // j+4+g <= 63 always
            int i1 = __shfl(cidx[n], j + 4 + g, 64);
            unsigned v0 = *(const unsigned*)(p + (size_t)i0 * 64 + c * 4);
            unsigned v1 = *(const unsigned*)(p + (size_t)i1 * 64 + c * 4);
            ACC(aA, v0) ACC(aA, v1)
        }
        for (int j = 16; j < dgB; j += 8) {
            int i0 = __shfl(cidx[n + 1], j + g, 64);
            int i1 = __shfl(cidx[n + 1], j + 4 + g, 64);
            unsigned v0 = *(const unsigned*)(p + (size_t)i0 * 64 + c * 4);
            unsigned v1 = *(const unsigned*)(p + (size_t)i1 * 64 + c * 4);
            ACC(aB, v0) ACC(aB, v1)
        }
        // --- deg>64 scalar tail (never fires for this input, kept for safety)
        for (int k = 64; k < dgA; ++k) {
            int r = col[rs[n] + k] & 0x1FFFF;
            unsigned v = *(const unsigned*)(p + (size_t)r * 64 + c * 4);
            if (g == 0) ACC(aA, v)
        }
        for (int k = 64; k < dgB; ++k) {
            int r = col[rs[n + 1] + k] & 0x1FFFF;
            unsigned v = *(const unsigned*)(p + (size_t)r * 64 + c * 4);
            if (g == 0) ACC(aB, v)
        }

        // --- cross-group reduce: 16 two-deep DS chains, interleaved ---
        aA.x += __shfl_xor(aA.x, 16, 64); aA.y += __shfl_xor(aA.y, 16, 64);
        aA.z += __shfl_xor(aA.z, 16, 64); aA.w += __shfl_xor(aA.w, 16, 64);
        aB.x += __shfl_xor(aB.x, 16, 64); aB.y += __shfl_xor(aB.y, 16, 64);
        aB.z += __shfl_xor(aB.z, 16, 64); aB.w += __shfl_xor(aB.w, 16, 64);
        aA.x += __shfl_xor(aA.x, 32, 64); aA.y += __shfl_xor(aA.y, 32, 64);
        aA.z += __shfl_xor(aA.z, 32, 64); aA.w += __shfl_xor(aA.w, 32, 64);
        aB.x += __shfl_xor(aB.x, 32, 64); aB.y += __shfl_xor(aB.y, 32, 64);
        aB.z += __shfl_xor(aB.z, 32, 64); aB.w += __shfl_xor(aB.w, 32, 64);

        // --- epilogue for both nodes ---
#pragma unroll
        for (int e = 0; e < 2; ++e) {
            int node = base_node + n + e;
            int dg = (e == 0) ? dgA : dgB;
            float4 a = (e == 0) ? aA : aB;
            float inv = 1.0f / fmaxf((float)dg, 1.0f);
            ushort4 qv = *(const ushort4*)(q + node * 64 + c * 4);
            float h0 = fmaxf(a.x * inv + b2v.x + bf2f(qv.x), 0.f);
            float h1 = fmaxf(a.y * inv + b2v.y + bf2f(qv.y), 0.f);
            float h2 = fmaxf(a.z * inv + b2v.z + bf2f(qv.z), 0.f);
            float h3 = fmaxf(a.w * inv + b2v.w + bf2f(qv.w), 0.f);

            float p0 = h0 * w01.x + h1 * w01.z + h2 * w23.x + h3 * w23.z;
            float p1 = h0 * w01.y + h1 * w01.w + h2 * w23.y + h3 * w23.w;
            if (g != 0) { p0 = 0.f; p1 = 0.f; }         // groups duplicate
            p0 += __shfl_down(p0, 8, 64);  p1 += __shfl_down(p1, 8, 64);
            p0 += __shfl_down(p0, 4, 64);  p1 += __shfl_down(p1, 4, 64);
            p0 += __shfl_down(p0, 2, 64);  p1 += __shfl_down(p1, 2, 64);
            p0 += __shfl_down(p0, 1, 64);  p1 += __shfl_down(p1, 1, 64);
            if (lane == 0) {
                int grp = batch[node];
                atomicAdd(&gsum[grp * 2 + 0], p0);
                atomicAdd(&gsum[grp * 2 + 1], p1);
            }
        }
    }
#undef ACC
}

// ---------------- finalize: out = gsum/cnt + bout ----------------
__global__ __launch_bounds__(256) void finalize_kernel(
    const float* __restrict__ gsum, const int* __restrict__ gstart,
    const float* __restrict__ bout, float* __restrict__ out)
{
    int g = blockIdx.x * 256 + threadIdx.x;
    if (g >= N_GRAPHS) return;
    int cnt = gstart[g + 1] - gstart[g];
    float inv = 1.0f / fmaxf((float)cnt, 1.0f);
    out[g * 2 + 0] = gsum[g * 2 + 0] * inv + bout[0];
    out[g * 2 + 1] = gsum[g * 2 + 1] * inv + bout[1];
}

extern "C" void kernel_launch(void* const* d_in, const int* in_sizes, int n_in,
                              void* d_out, int out_size, void* d_ws, size_t ws_size,
                              hipStream_t stream) {
    const int*   x    = (const int*)  d_in[0];
    const int*   ei   = (const int*)  d_in[1];
    const int*   batch= (const int*)  d_in[2];
    const float* emb  = (const float*)d_in[3];
    const float* W1l  = (const float*)d_in[4];
    const float* b1   = (const float*)d_in[5];
    const float* W1r  = (const float*)d_in[6];
    const float* W2l  = (const float*)d_in[7];
    const float* b2   = (const float*)d_in[8];
    const float* W2r  = (const float*)d_in[9];
    const float* Wout = (const float*)d_in[10];
    const float* bout = (const float*)d_in[11];
    float* out = (float*)d_out;

    const int* src = ei;
    const int* dst = ei + N_EDGES;

    char* ws = (char*)d_ws;
    size_t off = 0;
    unsigned char*  p8     = (unsigned char*) (ws + off); off += (size_t)N_NODES * 64 + 64; // +64B zero row
    unsigned short* q16    = (unsigned short*)(ws + off); off += (size_t)N_NODES * 64 * 2;  // 12.8 MB
    unsigned short* w2frag = (unsigned short*)(ws + off); off += (size_t)8192 * 2;
    float*    embW1l = (float*)   (ws + off); off += (size_t)VOCAB * 64 * 4;
    float*    embW1r = (float*)   (ws + off); off += (size_t)VOCAB * 64 * 4;
    int*      rowst  = (int*)     (ws + off); off += (size_t)N_NODES * 4;
    int*      deg    = (int*)     (ws + off); off += (size_t)N_NODES * 4;
    int*      col    = (int*)     (ws + off); off += (size_t)(NBK * CAP + 256) * 4;   // 6.4 MB
    unsigned* edge8  = (unsigned*)(ws + off); off += (size_t)NBK * CAP * 4;           // 6.4 MB
    int*      gstart = (int*)     (ws + off); off += (size_t)(N_GRAPHS + 1) * 4;
    // contiguous zero region: cursor | gsum (one memset)
    int*      cursor = (int*)     (ws + off); off += (size_t)NBK * 4;
    float*    gsum   = (float*)   (ws + off); off += (size_t)N_GRAPHS * 2 * 4;

    hipMemsetAsync(cursor, 0, (size_t)NBK * 4 + (size_t)N_GRAPHS * 2 * 4, stream);

    scatter_kernel<<<SCAT_BLOCKS + GB + 32, 256, 0, stream>>>(
        src, dst, x, cursor, edge8,
        batch, gstart, emb, W1l, W1r, W2l, W2r, embW1l, embW1r, w2frag, p8);
    csr_kernel<<<NBK, 256, 0, stream>>>(edge8, cursor, rowst, deg, col);
    sage1_kernel<<<N_NODES / (4 * S1_NPW), 256, 0, stream>>>(
        x, embW1l, embW1r, b1, rowst, deg, col, w2frag, p8, q16);
    sage2_kernel<<<N_NODES / (4 * S2_NPW), 256, 0, stream>>>(
        p8, q16, rowst, deg, col, b2, Wout, batch, gsum);
    finalize_kernel<<<(N_GRAPHS + 255) / 256, 256, 0, stream>>>(gsum, gstart, bout, out);
}